// Round 3
// baseline (222.535 us; speedup 1.0000x reference)
//
#include <hip/hip_runtime.h>
#include <math.h>

#define NB 4096
#define ND 1024
#define SCALEF 20.0f
#define TILES 32   // 4096 / 128 tiles per dimension
#define GRID (TILES * TILES)

typedef __bf16 bf16_t;
typedef bf16_t bf16x4 __attribute__((ext_vector_type(4)));
typedef bf16_t bf16x8 __attribute__((ext_vector_type(8)));
typedef float floatx4 __attribute__((ext_vector_type(4)));

__device__ __forceinline__ void load16_to_lds(const void* g, void* l) {
    __builtin_amdgcn_global_load_lds(
        (const __attribute__((address_space(1))) void*)g,
        (__attribute__((address_space(3))) void*)l, 16, 0, 0);
}

// ---------------------------------------------------------------------------
// Kernel 1: fused L2-normalize + fp32->bf16 convert. One wave per row.
// Also zeroes rowsum[] and the finalize counter (ws is poisoned each call).
// ---------------------------------------------------------------------------
__global__ __launch_bounds__(256) void mnrl_norm_cvt(
    const float* __restrict__ A, const float* __restrict__ P,
    bf16_t* __restrict__ Abf, bf16_t* __restrict__ Pbf,
    float* __restrict__ rowsum, int* __restrict__ counter) {
    int row = blockIdx.x * 4 + (threadIdx.x >> 6);  // 0..8191
    int lane = threadIdx.x & 63;
    bool is_a = row < NB;
    const float* src = is_a ? (A + (size_t)row * ND)
                            : (P + (size_t)(row - NB) * ND);
    bf16_t* dst = is_a ? (Abf + (size_t)row * ND)
                       : (Pbf + (size_t)(row - NB) * ND);

    float4 v[4];
    float ss = 0.0f;
#pragma unroll
    for (int i = 0; i < 4; ++i) {
        v[i] = ((const float4*)src)[i * 64 + lane];
        ss += v[i].x * v[i].x + v[i].y * v[i].y + v[i].z * v[i].z + v[i].w * v[i].w;
    }
#pragma unroll
    for (int off = 32; off > 0; off >>= 1) ss += __shfl_xor(ss, off, 64);
    float inv = 1.0f / fmaxf(sqrtf(ss), 1e-8f);
#pragma unroll
    for (int i = 0; i < 4; ++i) {
        bf16x4 w;
        w[0] = (bf16_t)(v[i].x * inv);
        w[1] = (bf16_t)(v[i].y * inv);
        w[2] = (bf16_t)(v[i].z * inv);
        w[3] = (bf16_t)(v[i].w * inv);
        ((bf16x4*)dst)[i * 64 + lane] = w;
    }
    if (is_a && lane == 0) rowsum[row] = 0.0f;
    if (blockIdx.x == 0 && threadIdx.x == 0) *counter = 0;
}

// ---------------------------------------------------------------------------
// Kernel 2: 128x128-tile bf16 MFMA GEMM + fused exp-sum + diag + last-block
// finalize. BK=32, DOUBLE-BUFFERED LDS (2 x 16 KB): loads for iter i+1 are
// issued right after iter i's barrier, so the barrier's vmcnt(0) drain only
// waits on loads that had a full iteration in flight.
// Swizzle: per row (32 k = 4 chunks of 8 bf16), chunk c lives at slot
// c^(row&3). DMA-write side is linear (conflict-free); frag-read side
// spreads 64 lanes evenly over all 32 banks (8 lanes per 4-bank group).
// ---------------------------------------------------------------------------
__global__ __launch_bounds__(256) void mnrl_gemm_lse(
    const bf16_t* __restrict__ Abf, const bf16_t* __restrict__ Pbf,
    float* __restrict__ rowsum, float* __restrict__ diag,
    int* __restrict__ counter, float* __restrict__ out) {
    __shared__ __align__(16) bf16_t lds_a[2 * 128 * 32];
    __shared__ __align__(16) bf16_t lds_b[2 * 128 * 32];

    // GROUP_M=8 swizzle for L2 locality
    int pid = blockIdx.x;
    const int num_in_group = 8 * TILES;
    int group_id = pid / num_in_group;
    int tile_m = group_id * 8 + (pid % 8);
    int tile_n = (pid % num_in_group) / 8;

    int t = threadIdx.x;
    int lane = t & 63;
    int wave = t >> 6;
    int wm = wave >> 1, wn = wave & 1;
    int quad = lane >> 4;
    int l16 = lane & 15;

    const bf16_t* Abase = Abf + (size_t)tile_m * 128 * ND;
    const bf16_t* Pbase = Pbf + (size_t)tile_n * 128 * ND;

    // Staging: issue j (= wave*2 + jj) covers rows j*16..j*16+15.
    // Lane l -> row-in-issue rl = l>>2, HW slot l&3; fetch global chunk
    // (l&3)^(rl&3) so slot s of row r holds chunk s^(r&3).
    int rl4 = lane >> 2;
    int cs4 = ((lane & 3) ^ (rl4 & 3)) * 8;   // element offset of fetched chunk
    // Frag read: row R has R&3 == l16&3.
    int swr = l16 & 3;

    floatx4 acc[4][4];
#pragma unroll
    for (int i = 0; i < 4; ++i)
#pragma unroll
        for (int j = 0; j < 4; ++j) acc[i][j] = (floatx4){0.f, 0.f, 0.f, 0.f};

    // Prologue: stage k=0 into buffer 0.
#pragma unroll
    for (int jj = 0; jj < 2; ++jj) {
        int j = wave * 2 + jj;
        int grow = j * 16 + rl4;
        load16_to_lds(Abase + (size_t)grow * ND + cs4, lds_a + j * 512);
        load16_to_lds(Pbase + (size_t)grow * ND + cs4, lds_b + j * 512);
    }

    for (int it = 0; it < ND / 32; ++it) {
        __syncthreads();  // drains loads issued last iter (full iter in flight)
        int kn = (it + 1) * 32;
        if (kn < ND) {
            bf16_t* la = lds_a + ((it + 1) & 1) * (128 * 32);
            bf16_t* lb = lds_b + ((it + 1) & 1) * (128 * 32);
#pragma unroll
            for (int jj = 0; jj < 2; ++jj) {
                int j = wave * 2 + jj;
                int grow = j * 16 + rl4;
                load16_to_lds(Abase + (size_t)grow * ND + kn + cs4, la + j * 512);
                load16_to_lds(Pbase + (size_t)grow * ND + kn + cs4, lb + j * 512);
            }
        }
        const bf16_t* ca = lds_a + (it & 1) * (128 * 32);
        const bf16_t* cb = lds_b + (it & 1) * (128 * 32);

        bf16x8 af[4], bfr[4];
#pragma unroll
        for (int mt = 0; mt < 4; ++mt) {
            int R = wm * 64 + mt * 16 + l16;
            af[mt] = *(const bf16x8*)&ca[R * 32 + ((quad ^ swr) * 8)];
        }
#pragma unroll
        for (int nt = 0; nt < 4; ++nt) {
            int R = wn * 64 + nt * 16 + l16;
            bfr[nt] = *(const bf16x8*)&cb[R * 32 + ((quad ^ swr) * 8)];
        }
#pragma unroll
        for (int mt = 0; mt < 4; ++mt)
#pragma unroll
            for (int nt = 0; nt < 4; ++nt)
                acc[mt][nt] = __builtin_amdgcn_mfma_f32_16x16x32_bf16(
                    af[mt], bfr[nt], acc[mt][nt], 0, 0, 0);
    }

    // Epilogue. C/D layout: col = l16, row = quad*4 + reg.
    int row0 = tile_m * 128 + wm * 64;
    int col0 = tile_n * 128 + wn * 64;
    bool diag_block = (tile_m == tile_n);

    float psum[4][4];
#pragma unroll
    for (int mt = 0; mt < 4; ++mt)
#pragma unroll
        for (int r = 0; r < 4; ++r) psum[mt][r] = 0.0f;

#pragma unroll
    for (int mt = 0; mt < 4; ++mt) {
#pragma unroll
        for (int nt = 0; nt < 4; ++nt) {
#pragma unroll
            for (int r = 0; r < 4; ++r) {
                float sc = SCALEF * acc[mt][nt][r];
                psum[mt][r] += __expf(sc - SCALEF);  // scores in [-20,20]
                if (diag_block) {
                    int grow = row0 + mt * 16 + quad * 4 + r;
                    int gcol = col0 + nt * 16 + l16;
                    if (grow == gcol) diag[grow] = sc;
                }
            }
        }
    }

#pragma unroll
    for (int mt = 0; mt < 4; ++mt) {
#pragma unroll
        for (int r = 0; r < 4; ++r) {
            float v = psum[mt][r];
            v += __shfl_xor(v, 1, 64);
            v += __shfl_xor(v, 2, 64);
            v += __shfl_xor(v, 4, 64);
            v += __shfl_xor(v, 8, 64);
            if (l16 == 0) atomicAdd(&rowsum[row0 + mt * 16 + quad * 4 + r], v);
        }
    }

    // -------- fused finalize: last block computes the loss ----------------
    __threadfence();
    __shared__ int is_last;
    if (t == 0) {
        int old = __hip_atomic_fetch_add(counter, 1, __ATOMIC_ACQ_REL,
                                         __HIP_MEMORY_SCOPE_AGENT);
        is_last = (old == GRID - 1);
    }
    __syncthreads();
    if (is_last) {
        float local = 0.0f;
        for (int i = t; i < NB; i += 256) {
            float rs = __hip_atomic_load(&rowsum[i], __ATOMIC_RELAXED,
                                         __HIP_MEMORY_SCOPE_AGENT);
            float dg = __hip_atomic_load(&diag[i], __ATOMIC_RELAXED,
                                         __HIP_MEMORY_SCOPE_AGENT);
            local += (logf(rs) + SCALEF) - dg;
        }
#pragma unroll
        for (int off = 32; off > 0; off >>= 1) local += __shfl_down(local, off, 64);
        __shared__ float sred[4];
        if ((t & 63) == 0) sred[t >> 6] = local;
        __syncthreads();
        if (t == 0) out[0] = (sred[0] + sred[1] + sred[2] + sred[3]) / (float)NB;
    }
}

// ---------------------------------------------------------------------------
extern "C" void kernel_launch(void* const* d_in, const int* in_sizes, int n_in,
                              void* d_out, int out_size, void* d_ws, size_t ws_size,
                              hipStream_t stream) {
    const float* A = (const float*)d_in[0];
    const float* P = (const float*)d_in[1];

    bf16_t* Abf = (bf16_t*)d_ws;                        // 8 MiB
    bf16_t* Pbf = Abf + (size_t)NB * ND;                // 8 MiB
    float* rowsum = (float*)(Pbf + (size_t)NB * ND);    // 16 KiB
    float* diag = rowsum + NB;                          // 16 KiB
    int* counter = (int*)(diag + NB);                   // 4 B

    mnrl_norm_cvt<<<2 * NB / 4, 256, 0, stream>>>(A, P, Abf, Pbf, rowsum, counter);
    mnrl_gemm_lse<<<GRID, 256, 0, stream>>>(Abf, Pbf, rowsum, diag, counter,
                                            (float*)d_out);
}